// Round 3
// baseline (28.875 us; speedup 1.0000x reference)
//
#include <hip/hip_runtime.h>
#include <math.h>

#define L_TAPS 16
#define M_FFT  64

// ---------------------------------------------------------------------------
// Kernel W: per-row weights (-> d_ws) and H_t (-> out tail).
// Block = 256 threads = 4 rows x 64 lanes.
// ---------------------------------------------------------------------------
__global__ __launch_bounds__(256) void weight_ht_kernel(
    const float* __restrict__ cr, const float* __restrict__ ci,
    const int*   __restrict__ ns_ptr,
    float2* __restrict__ ws,        // [NP*S] fused weights
    float*  __restrict__ out,       // H_t written at offset NP*SMK
    int NP, int SMK, int interleaved)
{
    __shared__ float2 s_tw[M_FFT];      // exp(-2*pi*i*j/64)
    __shared__ float  s_dop[L_TAPS];    // 2*pi*cos(angle_l)*fd
    __shared__ float2 s_cof[4][L_TAPS];

    const int tid  = threadIdx.x;
    const int S    = ns_ptr[0] + 2;     // N_PILOT = 2
    const int row0 = blockIdx.x * 4;
    const int row  = tid >> 6;          // 0..3
    const int lane = tid & 63;
    const int np   = row0 + row;

    const float two_pi = 6.2831853071795864f;

    if (tid < 64) {
        float sp, cp;
        __sincosf(-(float)tid * (two_pi / 64.0f), &sp, &cp);
        s_tw[tid] = make_float2(cp, sp);
    } else if (tid < 64 + L_TAPS) {
        int l = tid - 64;
        s_dop[l] = two_pi * __cosf(l * (two_pi / 15.0f)) * (100.0f / 3.0e8f * 3.0e9f);
    } else if (tid >= 128 && tid < 192) {
        int r = (tid - 128) >> 4;
        int l = tid & 15;
        int npp = row0 + r;
        if (npp < NP)
            s_cof[r][l] = make_float2(cr[(size_t)npp * L_TAPS + l],
                                      ci[(size_t)npp * L_TAPS + l]);
    }
    __syncthreads();

    if (np >= NP) return;

    // ---- H_t[m] = sum_l cof[l] * tw[(m*l) & 63] ----
    {
        const int m = lane;
        float hr = 0.f, hi = 0.f;
        #pragma unroll
        for (int l = 0; l < L_TAPS; ++l) {
            float2 c = s_cof[row][l];
            float2 t = s_tw[(m * l) & (M_FFT - 1)];
            hr += c.x * t.x - c.y * t.y;
            hi += c.x * t.y + c.y * t.x;
        }
        const size_t hbase = (size_t)NP * SMK;
        if (interleaved)
            ((float2*)out)[hbase + (size_t)np * M_FFT + m] = make_float2(hr, hi);
        else
            out[hbase + (size_t)np * M_FFT + m] = hr;   // real part only
    }

    // ---- weight[s] = sum_l cof[l] * exp(i * dop[l] * t_s) ----
    if (lane < S) {
        const float t = lane * (0.0005f / 14.0f);       // reference hard-codes /14
        float wr = 0.f, wi = 0.f;
        #pragma unroll
        for (int l = 0; l < L_TAPS; ++l) {
            float sp, cp;
            __sincosf(s_dop[l] * t, &sp, &cp);
            float2 c = s_cof[row][l];
            wr += c.x * cp - c.y * sp;
            wi += c.x * sp + c.y * cp;
        }
        ws[np * S + lane] = make_float2(wr, wi);
    }
}

// ---------------------------------------------------------------------------
// Kernel S: pure streaming  out[i] = Re(x[i] * w[i/MK'])  (float4, grid-stride)
// idx = (np*S + s)*MK + k  =>  weight index = idx / MK = v / (MK/4)
// ---------------------------------------------------------------------------
__global__ __launch_bounds__(256) void stream_kernel_v4(
    const float4* __restrict__ xr4, const float4* __restrict__ xi4,
    const float2* __restrict__ ws,
    float4* __restrict__ out4, int nvec, int mkq)
{
    const int stride = gridDim.x * blockDim.x;
    for (int v = blockIdx.x * blockDim.x + threadIdx.x; v < nvec; v += stride) {
        float4 a = xr4[v];
        float4 b = xi4[v];
        float2 w = ws[v / mkq];
        float4 r;
        r.x = a.x * w.x - b.x * w.y;
        r.y = a.y * w.x - b.y * w.y;
        r.z = a.z * w.x - b.z * w.y;
        r.w = a.w * w.x - b.w * w.y;
        out4[v] = r;
    }
}

// scalar fallback (also handles interleaved-complex output contract)
__global__ __launch_bounds__(256) void stream_kernel_scalar(
    const float* __restrict__ xr, const float* __restrict__ xi,
    const float2* __restrict__ ws,
    float* __restrict__ out, int n, int MK, int interleaved)
{
    const int stride = gridDim.x * blockDim.x;
    for (int i = blockIdx.x * blockDim.x + threadIdx.x; i < n; i += stride) {
        float2 w = ws[i / MK];
        float  a = xr[i], b = xi[i];
        if (interleaved)
            ((float2*)out)[i] = make_float2(a * w.x - b * w.y, a * w.y + b * w.x);
        else
            out[i] = a * w.x - b * w.y;
    }
}

extern "C" void kernel_launch(void* const* d_in, const int* in_sizes, int n_in,
                              void* d_out, int out_size, void* d_ws, size_t ws_size,
                              hipStream_t stream) {
    const float* xr = (const float*)d_in[0];
    const float* xi = (const float*)d_in[1];
    const float* cr = (const float*)d_in[2];
    const float* ci = (const float*)d_in[3];
    const int*   ns = (const int*)  d_in[4];

    const int NP  = in_sizes[2] / L_TAPS;   // N*P = 8192
    const int SMK = in_sizes[0] / NP;       // 1120

    const int elems = NP * SMK + NP * M_FFT;          // logical complex elements
    const int interleaved = (out_size == 2 * elems) ? 1 : 0;

    float2* ws  = (float2*)d_ws;
    float*  out = (float*)d_out;

    // Kernel W: weights + H_t
    weight_ht_kernel<<<(NP + 3) / 4, 256, 0, stream>>>(cr, ci, ns, ws, out,
                                                       NP, SMK, interleaved);

    // Kernel S: streaming multiply. MK = SMK/S is unknown on host (Ns lives on
    // device), but MK%4==0 and SMK%4==0 hold for the bench (MK=80, SMK=1120);
    // derive MK on host only to pick the path: S = Ns+2 is device-side, so we
    // conservatively use the vector path when SMK%4==0 and pass mkq via a tiny
    // trick: mkq must be computed on device?  No — MK depends only on S which
    // we cannot read here.  Instead: the scalar kernel reads MK... also device.
    // Resolution: pass SMK and let each kernel derive S from ns_ptr.
    (void)ws_size;
    // Use a wrapper that derives mkq on device: implemented below via a
    // dedicated kernel signature taking ns_ptr.
    // (see stream_dispatch)
    extern __global__ void stream_dispatch(const float4*, const float4*,
                                           const float2*, const int*,
                                           float*, int, int, int);
    stream_dispatch<<<2048, 256, 0, stream>>>((const float4*)xr, (const float4*)xi,
                                              ws, ns, out, NP, SMK, interleaved);
}

// Derives MK from device-side Ns, then does the float4 stream inline.
__global__ __launch_bounds__(256) void stream_dispatch(
    const float4* __restrict__ xr4, const float4* __restrict__ xi4,
    const float2* __restrict__ ws, const int* __restrict__ ns_ptr,
    float* __restrict__ out, int NP, int SMK, int interleaved)
{
    const int S  = ns_ptr[0] + 2;
    const int MK = SMK / S;
    const int n  = NP * SMK;
    const int stride = gridDim.x * blockDim.x;

    if (!interleaved && (MK & 3) == 0) {
        const int nvec = n >> 2;
        const int mkq  = MK >> 2;
        float4* out4 = (float4*)out;
        for (int v = blockIdx.x * blockDim.x + threadIdx.x; v < nvec; v += stride) {
            float4 a = xr4[v];
            float4 b = xi4[v];
            float2 w = ws[v / mkq];
            float4 r;
            r.x = a.x * w.x - b.x * w.y;
            r.y = a.y * w.x - b.y * w.y;
            r.z = a.z * w.x - b.z * w.y;
            r.w = a.w * w.x - b.w * w.y;
            out4[v] = r;
        }
    } else {
        const float* xr = (const float*)xr4;
        const float* xi = (const float*)xi4;
        for (int i = blockIdx.x * blockDim.x + threadIdx.x; i < n; i += stride) {
            float2 w = ws[i / MK];
            float  a = xr[i], b = xi[i];
            if (interleaved)
                ((float2*)out)[i] = make_float2(a * w.x - b * w.y, a * w.y + b * w.x);
            else
                out[i] = a * w.x - b * w.y;
        }
    }
}

// Round 4
// 25.591 us; speedup vs baseline: 1.1283x; 1.1283x over previous
//
#include <hip/hip_runtime.h>
#include <math.h>

#define L_TAPS 16
#define M_FFT  64
#define ROWS   4      // rows (n,p) per block
#define SMAX   128    // max supported S in LDS weight table

__global__ __launch_bounds__(256) void channel_fused(
    const float* __restrict__ xr, const float* __restrict__ xi,
    const float* __restrict__ cr, const float* __restrict__ ci,
    const int*   __restrict__ ns_ptr,
    float* __restrict__ out,          // [NP*SMK] real(out), then [NP*64] real(H_t)
    int NP, int SMK)
{
    __shared__ float2 s_tw[M_FFT];          // exp(-2*pi*i*j/64)
    __shared__ float  s_dop[L_TAPS];        // 2*pi*cos(angle_l)*fd
    __shared__ float2 s_cof[ROWS][L_TAPS];
    __shared__ float2 s_w[ROWS * SMAX];     // fused weights, slot = r*S + s

    const int tid  = threadIdx.x;
    const int S    = ns_ptr[0] + 2;         // N_PILOT = 2
    const int MK   = SMK / S;
    const int row0 = blockIdx.x * ROWS;

    const float two_pi = 6.2831853071795864f;

    // ---- phase 0: tables + cof staging (disjoint thread roles) ----
    if (tid < M_FFT) {
        float sp, cp;
        __sincosf(-(float)tid * (two_pi / (float)M_FFT), &sp, &cp);
        s_tw[tid] = make_float2(cp, sp);
    } else if (tid < M_FFT + L_TAPS) {
        int l = tid - M_FFT;
        s_dop[l] = two_pi * __cosf((float)l * (two_pi / (float)(L_TAPS - 1)))
                 * (100.0f / 3.0e8f * 3.0e9f);   // fd = 1000 Hz
    } else if (tid >= 128 && tid < 128 + ROWS * L_TAPS) {
        int r = (tid - 128) >> 4, l = tid & 15;
        int npp = row0 + r;
        if (npp < NP)
            s_cof[r][l] = make_float2(cr[(size_t)npp * L_TAPS + l],
                                      ci[(size_t)npp * L_TAPS + l]);
    }
    __syncthreads();

    // ---- phase 1: weights.  thread (s,l) computes e^{i*dop_l*t_s} ONCE,
    //      reuses it for all 4 rows; 16-lane shfl reduce over l. ----
    if (S <= SMAX) {
        const int l = tid & 15;
        for (int s = tid >> 4; s < S; s += 16) {
            float sp, cp;
            __sincosf(s_dop[l] * ((float)s * (0.0005f / 14.0f)), &sp, &cp);
            #pragma unroll
            for (int r = 0; r < ROWS; ++r) {
                float2 c = s_cof[r][l];
                float pr = c.x * cp - c.y * sp;
                float pi_ = c.x * sp + c.y * cp;
                #pragma unroll
                for (int off = 8; off; off >>= 1) {
                    pr  += __shfl_xor(pr,  off, 16);
                    pi_ += __shfl_xor(pi_, off, 16);
                }
                if (l == 0 && row0 + r < NP) s_w[r * S + s] = make_float2(pr, pi_);
            }
        }
    }

    // ---- H_t (no sync needed: reads only phase-0 data).  1 output/thread. ----
    {
        const int r = tid >> 6, m = tid & 63;
        const int npp = row0 + r;
        if (npp < NP) {
            float hr = 0.f;
            #pragma unroll
            for (int l = 0; l < L_TAPS; ++l) {
                float2 c = s_cof[r][l];
                float2 t = s_tw[(m * l) & (M_FFT - 1)];
                hr += c.x * t.x - c.y * t.y;    // real part only
            }
            out[(size_t)NP * SMK + (size_t)npp * M_FFT + m] = hr;
        }
    }
    __syncthreads();   // s_w ready

    // ---- phase 3: stream 4 contiguous rows as one flat coalesced range ----
    const int rows_here = min(ROWS, NP - row0);
    if (S <= SMAX && (MK & 3) == 0 && (SMK & 3) == 0) {
        const int   mkq   = MK >> 2;
        const int   limit = (rows_here * SMK) >> 2;
        const size_t gb   = (size_t)row0 * (SMK >> 2);
        const float4* xr4 = (const float4*)xr + gb;
        const float4* xi4 = (const float4*)xi + gb;
        float4*       o4  = (float4*)out + gb;
        for (int v = tid; v < limit; v += 256) {
            float4 a = xr4[v];
            float4 b = xi4[v];
            float2 w = s_w[(unsigned)v / (unsigned)mkq];   // = r*S + s
            float4 r4;
            r4.x = a.x * w.x - b.x * w.y;
            r4.y = a.y * w.x - b.y * w.y;
            r4.z = a.z * w.x - b.z * w.y;
            r4.w = a.w * w.x - b.w * w.y;
            o4[v] = r4;
        }
    } else if (S <= SMAX) {
        const size_t gb = (size_t)row0 * SMK;
        const int limit = rows_here * SMK;
        for (int i = tid; i < limit; i += 256) {
            float2 w = s_w[(unsigned)i / (unsigned)MK];
            out[gb + i] = xr[gb + i] * w.x - xi[gb + i] * w.y;
        }
    } else {
        // ultra-fallback (S > SMAX): recompute weight per element. Never hit
        // in the bench (S = 14); correctness-only path.
        const size_t gb = (size_t)row0 * SMK;
        const int limit = rows_here * SMK;
        for (int i = tid; i < limit; i += 256) {
            int r = i / SMK, s = (i - r * SMK) / MK;
            float wr = 0.f, wi = 0.f;
            #pragma unroll
            for (int l = 0; l < L_TAPS; ++l) {
                float sp, cp;
                __sincosf(s_dop[l] * ((float)s * (0.0005f / 14.0f)), &sp, &cp);
                float2 c = s_cof[r][l];
                wr += c.x * cp - c.y * sp;
                wi += c.x * sp + c.y * cp;
            }
            out[gb + i] = xr[gb + i] * wr - xi[gb + i] * wi;
        }
    }
}

extern "C" void kernel_launch(void* const* d_in, const int* in_sizes, int n_in,
                              void* d_out, int out_size, void* d_ws, size_t ws_size,
                              hipStream_t stream) {
    const float* xr = (const float*)d_in[0];
    const float* xi = (const float*)d_in[1];
    const float* cr = (const float*)d_in[2];
    const float* ci = (const float*)d_in[3];
    const int*   ns = (const int*)  d_in[4];

    const int NP  = in_sizes[2] / L_TAPS;   // N*P = 8192
    const int SMK = in_sizes[0] / NP;       // 1120
    (void)d_ws; (void)ws_size; (void)out_size; (void)n_in;

    channel_fused<<<(NP + ROWS - 1) / ROWS, 256, 0, stream>>>(
        xr, xi, cr, ci, ns, (float*)d_out, NP, SMK);
}

// Round 5
// 24.601 us; speedup vs baseline: 1.1737x; 1.0402x over previous
//
#include <hip/hip_runtime.h>
#include <math.h>

#define L_TAPS 16
#define M_FFT  64
#define ROWS   4      // rows (n,p) per block
#define SMAX   128    // max supported S in LDS weight table

typedef float v4f __attribute__((ext_vector_type(4)));

__global__ __launch_bounds__(256) void channel_fused(
    const float* __restrict__ xr, const float* __restrict__ xi,
    const float* __restrict__ cr, const float* __restrict__ ci,
    const int*   __restrict__ ns_ptr,
    float* __restrict__ out,          // [NP*SMK] real(out), then [NP*64] real(H_t)
    int NP, int SMK)
{
    __shared__ float2 s_tw[M_FFT];          // exp(-2*pi*i*j/64)
    __shared__ float2 s_cof[ROWS][L_TAPS];
    __shared__ float2 s_w[ROWS * SMAX];     // fused weights, slot = r*S + s

    const int tid  = threadIdx.x;
    const int S    = ns_ptr[0] + 2;         // N_PILOT = 2
    const int MK   = SMK / S;
    const int row0 = blockIdx.x * ROWS;
    const float two_pi = 6.2831853071795864f;

    // ---- phase 0: cof staging + twiddle table (disjoint roles) ----
    if (tid < ROWS * L_TAPS) {
        int r = tid >> 4, l = tid & 15;
        int npp = row0 + r;
        if (npp < NP)
            s_cof[r][l] = make_float2(cr[(size_t)npp * L_TAPS + l],
                                      ci[(size_t)npp * L_TAPS + l]);
    } else if (tid < 64 + M_FFT) {
        int m = tid - 64;
        float sp, cp;
        __sincosf(-(float)m * (two_pi / (float)M_FFT), &sp, &cp);
        s_tw[m] = make_float2(cp, sp);
    }
    __syncthreads();

    // ---- phase 1a: weights. threads >=128, one (r,s) each, serial 16 sincos ----
    if (S <= SMAX && tid >= 128) {
        for (int q = tid - 128; q < ROWS * S; q += 128) {
            int r = q / S;
            int s = q - r * S;
            if (row0 + r < NP) {
                float t = (float)s * (0.0005f / 14.0f);   // reference hard-codes /14
                float wr = 0.f, wi = 0.f;
                #pragma unroll
                for (int l = 0; l < L_TAPS; ++l) {
                    float dop = two_pi
                              * __cosf((float)l * (two_pi / (float)(L_TAPS - 1)))
                              * 1000.0f;                  // fd = V/c*fc = 1000 Hz
                    float sp, cp;
                    __sincosf(dop * t, &sp, &cp);
                    float2 c = s_cof[r][l];
                    wr += c.x * cp - c.y * sp;
                    wi += c.x * sp + c.y * cp;
                }
                s_w[q] = make_float2(wr, wi);
            }
        }
    }

    // ---- phase 1b: H_t, one output per thread (reads only phase-0 LDS) ----
    {
        int r = tid >> 6, m = tid & 63;
        int npp = row0 + r;
        if (npp < NP) {
            float hr = 0.f;
            #pragma unroll
            for (int l = 0; l < L_TAPS; ++l) {
                float2 c = s_cof[r][l];
                float2 t = s_tw[(m * l) & (M_FFT - 1)];
                hr += c.x * t.x - c.y * t.y;              // real part only
            }
            out[(size_t)NP * SMK + (size_t)npp * M_FFT + m] = hr;
        }
    }
    __syncthreads();   // s_w ready

    // ---- phase 2: stream ROWS contiguous rows, static-unrolled, NT ----
    const int rows_here = min(ROWS, NP - row0);
    if (S <= SMAX && (MK & 3) == 0 && (SMK & 3) == 0 && rows_here == ROWS) {
        const unsigned mkq = (unsigned)(MK >> 2);
        const int nvr   = SMK >> 2;
        const int limit = ROWS * nvr;            // 1120 in bench
        const size_t gb = (size_t)row0 * nvr;
        const v4f* xr4 = (const v4f*)xr + gb;
        const v4f* xi4 = (const v4f*)xi + gb;
        v4f*       o4  = (v4f*)out + gb;
        const int niters = limit >> 8;           // 4 in bench

        int j = 0;
        for (; j + 4 <= niters; j += 4) {        // compile-time-unrolled block
            const int v0 = (j << 8) + tid, v1 = v0 + 256, v2 = v0 + 512, v3 = v0 + 768;
            v4f a0 = __builtin_nontemporal_load(xr4 + v0);
            v4f a1 = __builtin_nontemporal_load(xr4 + v1);
            v4f a2 = __builtin_nontemporal_load(xr4 + v2);
            v4f a3 = __builtin_nontemporal_load(xr4 + v3);
            v4f b0 = __builtin_nontemporal_load(xi4 + v0);
            v4f b1 = __builtin_nontemporal_load(xi4 + v1);
            v4f b2 = __builtin_nontemporal_load(xi4 + v2);
            v4f b3 = __builtin_nontemporal_load(xi4 + v3);
            float2 w0 = s_w[(unsigned)v0 / mkq];
            float2 w1 = s_w[(unsigned)v1 / mkq];
            float2 w2 = s_w[(unsigned)v2 / mkq];
            float2 w3 = s_w[(unsigned)v3 / mkq];
            __builtin_nontemporal_store(a0 * w0.x - b0 * w0.y, o4 + v0);
            __builtin_nontemporal_store(a1 * w1.x - b1 * w1.y, o4 + v1);
            __builtin_nontemporal_store(a2 * w2.x - b2 * w2.y, o4 + v2);
            __builtin_nontemporal_store(a3 * w3.x - b3 * w3.y, o4 + v3);
        }
        for (; j < niters; ++j) {                // leftover uniform iters
            const int v = (j << 8) + tid;
            v4f a = __builtin_nontemporal_load(xr4 + v);
            v4f b = __builtin_nontemporal_load(xi4 + v);
            float2 w = s_w[(unsigned)v / mkq];
            __builtin_nontemporal_store(a * w.x - b * w.y, o4 + v);
        }
        const int t = (niters << 8) + tid;       // tail: 96 threads in bench
        if (t < limit) {
            v4f a = __builtin_nontemporal_load(xr4 + t);
            v4f b = __builtin_nontemporal_load(xi4 + t);
            float2 w = s_w[(unsigned)t / mkq];
            __builtin_nontemporal_store(a * w.x - b * w.y, o4 + t);
        }
    } else if (S <= SMAX) {
        // generic scalar path (partial block / odd MK)
        const size_t gb = (size_t)row0 * SMK;
        const int limit = rows_here * SMK;
        for (int i = tid; i < limit; i += 256) {
            float2 w = s_w[(unsigned)i / (unsigned)MK];
            out[gb + i] = xr[gb + i] * w.x - xi[gb + i] * w.y;
        }
    } else {
        // S > SMAX: recompute weight per element — correctness-only path
        const size_t gb = (size_t)row0 * SMK;
        const int limit = rows_here * SMK;
        for (int i = tid; i < limit; i += 256) {
            int r = i / SMK, s = (i - r * SMK) / MK;
            float t = (float)s * (0.0005f / 14.0f);
            float wr = 0.f, wi = 0.f;
            #pragma unroll
            for (int l = 0; l < L_TAPS; ++l) {
                float dop = two_pi
                          * __cosf((float)l * (two_pi / (float)(L_TAPS - 1)))
                          * 1000.0f;
                float sp, cp;
                __sincosf(dop * t, &sp, &cp);
                float2 c = s_cof[r][l];
                wr += c.x * cp - c.y * sp;
                wi += c.x * sp + c.y * cp;
            }
            out[gb + i] = xr[gb + i] * wr - xi[gb + i] * wi;
        }
    }
}

extern "C" void kernel_launch(void* const* d_in, const int* in_sizes, int n_in,
                              void* d_out, int out_size, void* d_ws, size_t ws_size,
                              hipStream_t stream) {
    const float* xr = (const float*)d_in[0];
    const float* xi = (const float*)d_in[1];
    const float* cr = (const float*)d_in[2];
    const float* ci = (const float*)d_in[3];
    const int*   ns = (const int*)  d_in[4];

    const int NP  = in_sizes[2] / L_TAPS;   // N*P = 8192
    const int SMK = in_sizes[0] / NP;       // 1120
    (void)d_ws; (void)ws_size; (void)out_size; (void)n_in;

    channel_fused<<<(NP + ROWS - 1) / ROWS, 256, 0, stream>>>(
        xr, xi, cr, ci, ns, (float*)d_out, NP, SMK);
}